// Round 1
// baseline (1075.177 us; speedup 1.0000x reference)
//
#include <hip/hip_runtime.h>

#define NN 100000
#define EE 600000
#define DD 164
#define HH 2
#define DKK 82
#define EDIM 16
#define TDIM 8
#define STEP 30000
#define NC 20          // EE / STEP
#define FEAT 24        // EDIM + TDIM
#define HID 82         // D/2
#define NG 41          // DD/4 float4 groups
#define KP 96          // padded K for MFMA (82 -> 96)
#define MP 336         // padded M (2*164 -> 336)
#define NBLK ((EE + 255) / 256)

typedef __attribute__((ext_vector_type(8))) short short8;
typedef __attribute__((ext_vector_type(4))) float floatx4;

__device__ __forceinline__ float fast_tanh(float x) {
    float e = __expf(2.0f * x);
    return 1.0f - 2.0f * __builtin_amdgcn_rcpf(e + 1.0f);
}

__device__ __forceinline__ short f2bf(float f) {
    union { float f; unsigned u; } x; x.f = f;
    unsigned r = x.u + 0x7fffu + ((x.u >> 16) & 1u);   // RNE
    return (short)(r >> 16);
}

// ---------------- one-time weight prep: W2 -> pair-interleaved bf16, b2 -> permuted ----------------
// W2p[2d+p][k] = bf16(W2[d + p*164][k]), zero-padded to [336][96]; b2p[2d+p] = b2[d+p*164]

__global__ void __launch_bounds__(256) prep_w2_kernel(
    const float* __restrict__ W2, const float* __restrict__ b2,
    short* __restrict__ W2p, float* __restrict__ b2p)
{
    int idx = blockIdx.x * 256 + threadIdx.x;
    if (idx < MP * KP) {
        int m = idx / KP, kk = idx - m * KP;
        float val = 0.f;
        if (m < 2 * DD && kk < HID) {
            int dth = m >> 1, p = m & 1;
            val = W2[(size_t)(dth + p * DD) * HID + kk];
        }
        W2p[idx] = f2bf(val);
    }
    if (idx < MP) {
        float bv = 0.f;
        if (idx < 2 * DD) { int dth = idx >> 1, p = idx & 1; bv = b2[dth + p * DD]; }
        b2p[idx] = bv;
    }
}

// ---------------- CSR build ----------------

__global__ void __launch_bounds__(256) zero2_kernel(int* __restrict__ a, int* __restrict__ b, int n) {
    int i = blockIdx.x * 256 + threadIdx.x;
    if (i < n) { a[i] = 0; b[i] = 0; }
}

__global__ void __launch_bounds__(256) count_kernel(const int* __restrict__ ei, int* __restrict__ deg) {
    int e = blockIdx.x * 256 + threadIdx.x;
    if (e < EE) atomicAdd(&deg[ei[EE + e]], 1);
}

__global__ void __launch_bounds__(256) scan_kernel(const int* __restrict__ deg, int* __restrict__ off) {
    const int CH = (NN + 255) / 256;
    int t = threadIdx.x;
    int beg = t * CH, end = min(beg + CH, NN);
    int s = 0;
    for (int i = beg; i < end; ++i) s += deg[i];
    __shared__ int sums[256];
    sums[t] = s;
    __syncthreads();
    for (int d = 1; d < 256; d <<= 1) {
        int val = (t >= d) ? sums[t - d] : 0;
        __syncthreads();
        sums[t] += val;
        __syncthreads();
    }
    int run = (t == 0) ? 0 : sums[t - 1];
    for (int i = beg; i < end; ++i) { off[i] = run; run += deg[i]; }
    if (t == 255) off[NN] = run;
}

__global__ void __launch_bounds__(256) fill_kernel(const int* __restrict__ ei,
                                                   const int* __restrict__ off,
                                                   int* __restrict__ cnt,
                                                   int* __restrict__ elist) {
    int e = blockIdx.x * 256 + threadIdx.x;
    if (e >= EE) return;
    int d = ei[EE + e];
    int p = atomicAdd(&cnt[d], 1);
    elist[off[d] + p] = e;
}

// ---------------- score + chunk softmax denom ----------------

__global__ void __launch_bounds__(256) score_kernel(
    const float* __restrict__ q, const float* __restrict__ k,
    const int* __restrict__ ei, const float* __restrict__ rel_bias,
    float* __restrict__ escore)
{
    int e = blockIdx.x * 256 + threadIdx.x;
    if (e >= EE) return;
    int s = ei[e];
    int d = ei[EE + e];
    const float4* qr = (const float4*)(q + (size_t)d * DD);
    const float4* kr = (const float4*)(k + (size_t)s * DD);
    float s0 = 0.f, s1 = 0.f;
    #pragma unroll 4
    for (int i = 0; i < 20; ++i) {
        float4 a = qr[i], b = kr[i];
        s0 += a.x * b.x; s0 += a.y * b.y; s0 += a.z * b.z; s0 += a.w * b.w;
    }
    {
        float4 a = qr[20], b = kr[20];
        s0 += a.x * b.x + a.y * b.y;
        s1 += a.z * b.z + a.w * b.w;
    }
    #pragma unroll 4
    for (int i = 21; i < 41; ++i) {
        float4 a = qr[i], b = kr[i];
        s1 += a.x * b.x; s1 += a.y * b.y; s1 += a.z * b.z; s1 += a.w * b.w;
    }
    const float inv_sqrt = 0.11043152607484654f;  // 1/sqrt(82)
    escore[2 * e]     = __expf(s0 * inv_sqrt + rel_bias[0]);
    escore[2 * e + 1] = __expf(s1 * inv_sqrt + rel_bias[1]);
}

__global__ void __launch_bounds__(256) chunkinv_kernel(
    const float* __restrict__ escore, float* __restrict__ invsum)
{
    int c = blockIdx.x, h = blockIdx.y;
    const float* base = escore + (size_t)c * STEP * 2 + h;
    float acc = 0.f;
    for (int i = threadIdx.x; i < STEP; i += 256) acc += base[2 * i];
    __shared__ float red[256];
    red[threadIdx.x] = acc;
    __syncthreads();
    for (int s2 = 128; s2 > 0; s2 >>= 1) {
        if (threadIdx.x < s2) red[threadIdx.x] += red[threadIdx.x + s2];
        __syncthreads();
    }
    if (threadIdx.x == 0) invsum[c * 2 + h] = 1.0f / red[0];
}

__global__ void __launch_bounds__(256) zero_kernel(float4* __restrict__ p, int n4) {
    int i = blockIdx.x * 256 + threadIdx.x;
    if (i < n4) p[i] = make_float4(0.f, 0.f, 0.f, 0.f);
}

// ---------------- main: hmid (VALU) -> LDS bf16 -> MFMA W2 GEMM -> epilogue + segment reduce ----
// GEMM computes gb[m=permuted gamma/beta dim][n=edge in block]:
//   A = W2p (global bf16, [336][96]), B = hmid_lds ([256 edges][96] bf16)
// A-frag (16x16x32): lane holds A[mt*16 + (lane&15)][ks*32 + (lane>>4)*8 + j], j=0..7
// B-frag:            lane holds B'[k][n]: hmid[wavebase + nt*16 + (lane&15)][same k]
// C/D:               col n = lane&15, row m = (lane>>4)*4 + r
// With pair-interleaved W2p rows, lane's 4 C-values = (gamma,beta) for dims d0, d0+1, d0 = mt*8 + (lane>>4)*2.

__global__ void __launch_bounds__(256) main_mfma_kernel(
    const float* __restrict__ v, const int* __restrict__ ei,
    const float* __restrict__ edge_attr, const float* __restrict__ edge_time,
    const float* __restrict__ Wt, const float* __restrict__ bt,
    const float* __restrict__ W1, const float* __restrict__ b1,
    const short* __restrict__ W2p, const float* __restrict__ b2p,
    const float* __restrict__ escore, const float* __restrict__ invsum,
    const int* __restrict__ off, const int* __restrict__ elist,
    float* __restrict__ out)
{
    __shared__ short hmid_lds[256 * KP];   // 48 KB, row-major [edge][k] bf16
    __shared__ float res_lds[256 * 8];     // 8 KB, [edge][8 dims of current mt]
    __shared__ int   sdst[256];
    __shared__ int   ssrc[256];
    __shared__ float satt[512];

    const int tid = threadIdx.x;
    const int gid = blockIdx.x * 256 + tid;
    const bool valid = gid < EE;
    const int gi = valid ? gid : (EE - 1);
    const int e = elist[gi];
    const int s = ei[e];
    const int d = ei[EE + e];
    sdst[tid] = valid ? d : -1;
    ssrc[tid] = s;
    {
        unsigned c = (unsigned)e / STEP;
        satt[2 * tid]     = escore[2 * e]     * invsum[2 * c];
        satt[2 * tid + 1] = escore[2 * e + 1] * invsum[2 * c + 1];
    }

    // ---- feat ----
    float feat[FEAT];
    const float4* ea4 = (const float4*)(edge_attr + (size_t)e * EDIM);
    #pragma unroll
    for (int i = 0; i < 4; ++i) {
        float4 a = ea4[i];
        feat[4 * i + 0] = a.x; feat[4 * i + 1] = a.y;
        feat[4 * i + 2] = a.z; feat[4 * i + 3] = a.w;
    }
    float t = edge_time[e];
    #pragma unroll
    for (int j = 0; j < TDIM; ++j) feat[EDIM + j] = t * Wt[j] + bt[j];

    // ---- hmid in 8-wide chunks -> bf16 -> LDS (low register pressure, no spills) ----
    #pragma unroll 1
    for (int oc = 0; oc < KP / 8; ++oc) {
        union { short h[8]; int4 v4; } pk;
        #pragma unroll
        for (int j = 0; j < 8; ++j) {
            int o = oc * 8 + j;
            float acc = 0.f;
            if (o < HID) {
                acc = b1[o];
                #pragma unroll
                for (int f = 0; f < FEAT; ++f) acc = fmaf(feat[f], W1[o * FEAT + f], acc);
                acc = fmaxf(acc, 0.f);
            }
            pk.h[j] = f2bf(acc);
        }
        *(int4*)&hmid_lds[tid * KP + oc * 8] = pk.v4;
    }
    __syncthreads();

    const int lane = tid & 63;
    const int wavebase = tid & ~63;
    const int lrow = lane & 15;
    const int quad = lane >> 4;

    // ---- B fragments: persistent across the whole mt loop (12 x 4 VGPRs) ----
    short8 bfrag[4][3];
    #pragma unroll
    for (int nt = 0; nt < 4; ++nt)
        #pragma unroll
        for (int ks = 0; ks < 3; ++ks)
            bfrag[nt][ks] = *(const short8*)&hmid_lds[(wavebase + nt * 16 + lrow) * KP + ks * 32 + quad * 8];

    // ---- leader metadata (dst-sorted segments, round-3 proven) ----
    bool leader = valid && (tid == 0 || sdst[tid - 1] != d);
    int seglen = 0;
    bool interior = false;
    float* orow = nullptr;
    if (leader) {
        while (tid + seglen < 256 && sdst[tid + seglen] == d) ++seglen;
        int bs = blockIdx.x * 256;
        interior = (off[d] >= bs) && (off[d + 1] <= bs + 256);
        orow = out + (size_t)d * DD;
    }

    #pragma unroll 1
    for (int mt = 0; mt < 21; ++mt) {
        short8 afrag[3];
        #pragma unroll
        for (int ks = 0; ks < 3; ++ks)
            afrag[ks] = *(const short8*)&W2p[(mt * 16 + lrow) * KP + ks * 32 + quad * 8];

        floatx4 acc[4];
        #pragma unroll
        for (int nt = 0; nt < 4; ++nt) acc[nt] = (floatx4)(0.f);
        #pragma unroll
        for (int ks = 0; ks < 3; ++ks)
            #pragma unroll
            for (int nt = 0; nt < 4; ++nt)
                acc[nt] = __builtin_amdgcn_mfma_f32_16x16x32_bf16(afrag[ks], bfrag[nt][ks], acc[nt], 0, 0, 0);

        float4 bias = *(const float4*)&b2p[mt * 16 + quad * 4];
        int d0 = mt * 8 + quad * 2;

        #pragma unroll
        for (int nt = 0; nt < 4; ++nt) {
            int e_loc = wavebase + nt * 16 + lrow;
            float r0 = 0.f, r1 = 0.f;
            if (d0 < DD) {
                float g0  = fast_tanh(acc[nt][0] + bias.x);
                float be0 = fast_tanh(acc[nt][1] + bias.y);
                float g1  = fast_tanh(acc[nt][2] + bias.z);
                float be1 = fast_tanh(acc[nt][3] + bias.w);
                int s_e = ssrc[e_loc];
                const float* vp = v + (size_t)s_e * DD + d0;
                float v0 = vp[0], v1 = vp[1];
                float a0 = satt[2 * e_loc + (d0 >= DKK ? 1 : 0)];
                float a1 = satt[2 * e_loc + (d0 + 1 >= DKK ? 1 : 0)];
                r0 = a0 * (v0 * (1.f + g0) + be0);
                r1 = a1 * (v1 * (1.f + g1) + be1);
            }
            res_lds[e_loc * 8 + quad * 2]     = r0;
            res_lds[e_loc * 8 + quad * 2 + 1] = r1;
        }
        __syncthreads();

        if (leader) {
            float4 s0 = make_float4(0.f, 0.f, 0.f, 0.f);
            float4 s1 = make_float4(0.f, 0.f, 0.f, 0.f);
            for (int t2 = 0; t2 < seglen; ++t2) {
                const float4* rp = (const float4*)&res_lds[(tid + t2) * 8];
                float4 a = rp[0], b = rp[1];
                s0.x += a.x; s0.y += a.y; s0.z += a.z; s0.w += a.w;
                s1.x += b.x; s1.y += b.y; s1.z += b.z; s1.w += b.w;
            }
            int D0 = mt * 8;
            if (interior) {
                *(float4*)(orow + D0) = s0;
                if (D0 + 4 < DD) *(float4*)(orow + D0 + 4) = s1;
            } else {
                unsafeAtomicAdd(orow + D0 + 0, s0.x);
                unsafeAtomicAdd(orow + D0 + 1, s0.y);
                unsafeAtomicAdd(orow + D0 + 2, s0.z);
                unsafeAtomicAdd(orow + D0 + 3, s0.w);
                if (D0 + 4 < DD) {
                    unsafeAtomicAdd(orow + D0 + 4, s1.x);
                    unsafeAtomicAdd(orow + D0 + 5, s1.y);
                    unsafeAtomicAdd(orow + D0 + 6, s1.z);
                    unsafeAtomicAdd(orow + D0 + 7, s1.w);
                }
            }
        }
        __syncthreads();
    }
}

// ---------------- fallback (proved-correct round-1 atomic path) ----------------

__global__ void __launch_bounds__(256) main_atomic_kernel(
    const float* __restrict__ v, const int* __restrict__ ei,
    const float* __restrict__ edge_attr, const float* __restrict__ edge_time,
    const float* __restrict__ Wt, const float* __restrict__ bt,
    const float* __restrict__ W1, const float* __restrict__ b1,
    const float* __restrict__ W2, const float* __restrict__ b2,
    const float* __restrict__ escore, const float* __restrict__ invsum,
    float* __restrict__ out)
{
    int e = blockIdx.x * 256 + threadIdx.x;
    if (e >= EE) return;
    int s = ei[e];
    int d = ei[EE + e];
    float feat[FEAT];
    const float4* ea4 = (const float4*)(edge_attr + (size_t)e * EDIM);
    #pragma unroll
    for (int i = 0; i < 4; ++i) {
        float4 a = ea4[i];
        feat[4 * i + 0] = a.x; feat[4 * i + 1] = a.y;
        feat[4 * i + 2] = a.z; feat[4 * i + 3] = a.w;
    }
    float t = edge_time[e];
    #pragma unroll
    for (int j = 0; j < TDIM; ++j) feat[EDIM + j] = t * Wt[j] + bt[j];
    float hmid[HID];
    #pragma unroll
    for (int o = 0; o < HID; ++o) {
        float acc = b1[o];
        #pragma unroll
        for (int f = 0; f < FEAT; ++f) acc = fmaf(feat[f], W1[o * FEAT + f], acc);
        hmid[o] = fmaxf(acc, 0.f);
    }
    int c = e / STEP;
    float att0 = escore[2 * e]     * invsum[2 * c];
    float att1 = escore[2 * e + 1] * invsum[2 * c + 1];
    const float4* vrow4 = (const float4*)(v + (size_t)s * DD);
    float* orow = out + (size_t)d * DD;
    #pragma unroll 1
    for (int j = 0; j < NG; ++j) {
        float4 vv = vrow4[j];
        float vvals[4] = {vv.x, vv.y, vv.z, vv.w};
        float res[4];
        #pragma unroll
        for (int u = 0; u < 4; ++u) {
            int dd = 4 * j + u;
            float ga = b2[dd];
            float bb = b2[dd + DD];
            #pragma unroll
            for (int o = 0; o < HID; ++o) {
                ga = fmaf(hmid[o], W2[dd * HID + o], ga);
                bb = fmaf(hmid[o], W2[(dd + DD) * HID + o], bb);
            }
            float gamma = fast_tanh(ga);
            float beta  = fast_tanh(bb);
            float vh = vvals[u] * (1.f + gamma) + beta;
            res[u] = ((dd < DKK) ? att0 : att1) * vh;
        }
        unsafeAtomicAdd(orow + 4 * j + 0, res[0]);
        unsafeAtomicAdd(orow + 4 * j + 1, res[1]);
        unsafeAtomicAdd(orow + 4 * j + 2, res[2]);
        unsafeAtomicAdd(orow + 4 * j + 3, res[3]);
    }
}

// ---------------- launch ----------------

extern "C" void kernel_launch(void* const* d_in, const int* in_sizes, int n_in,
                              void* d_out, int out_size, void* d_ws, size_t ws_size,
                              hipStream_t stream) {
    const float* q   = (const float*)d_in[0];
    const float* k   = (const float*)d_in[1];
    const float* v   = (const float*)d_in[2];
    const int*   ei  = (const int*)d_in[3];
    const float* ea  = (const float*)d_in[4];
    const float* et  = (const float*)d_in[5];
    const float* Wt  = (const float*)d_in[6];
    const float* bt  = (const float*)d_in[7];
    const float* W1  = (const float*)d_in[8];
    const float* b1  = (const float*)d_in[9];
    const float* W2  = (const float*)d_in[10];
    const float* b2  = (const float*)d_in[11];
    const float* rb  = (const float*)d_in[12];
    float* out = (float*)d_out;

    // ws layout (16-B aligned chunks), ~9.7 MB total
    short* W2p    = (short*)d_ws;                       // 336*96 shorts = 64512 B
    float* b2p    = (float*)(W2p + MP * KP);            // 336 floats = 1344 B
    float* escore = b2p + MP;                           // 2*EE
    float* invsum = escore + (size_t)2 * EE;            // 64 (padded)
    int*   deg    = (int*)(invsum + 64);                // NN
    int*   off    = deg + NN;                           // NN+1
    int*   cnt    = off + NN + 1;                       // NN
    int*   elist  = cnt + NN;                           // EE

    size_t need = (size_t)(MP * KP) * 2 + (MP + 2 * EE + 64) * 4 +
                  ((size_t)3 * NN + 1 + EE) * 4;

    int n4 = out_size / 4;
    zero_kernel<<<(n4 + 255) / 256, 256, 0, stream>>>((float4*)out, n4);

    if (ws_size >= need) {
        prep_w2_kernel<<<(MP * KP + 255) / 256, 256, 0, stream>>>(W2, b2, W2p, b2p);
        score_kernel<<<NBLK, 256, 0, stream>>>(q, k, ei, rb, escore);
        chunkinv_kernel<<<dim3(NC, HH), 256, 0, stream>>>(escore, invsum);
        zero2_kernel<<<(NN + 255) / 256, 256, 0, stream>>>(deg, cnt, NN);
        count_kernel<<<NBLK, 256, 0, stream>>>(ei, deg);
        scan_kernel<<<1, 256, 0, stream>>>(deg, off);
        fill_kernel<<<NBLK, 256, 0, stream>>>(ei, off, cnt, elist);
        main_mfma_kernel<<<NBLK, 256, 0, stream>>>(
            v, ei, ea, et, Wt, bt, W1, b1, W2p, b2p, escore, invsum, off, elist, out);
    } else {
        float* escore_f = (float*)d_ws;
        float* invsum_f = escore_f + (size_t)2 * EE;
        score_kernel<<<NBLK, 256, 0, stream>>>(q, k, ei, rb, escore_f);
        chunkinv_kernel<<<dim3(NC, HH), 256, 0, stream>>>(escore_f, invsum_f);
        main_atomic_kernel<<<NBLK, 256, 0, stream>>>(
            v, ei, ea, et, Wt, bt, W1, b1, W2, b2, escore_f, invsum_f, out);
    }
}

// Round 2
// 1033.874 us; speedup vs baseline: 1.0400x; 1.0400x over previous
//
#include <hip/hip_runtime.h>

#define NN 100000
#define EE 600000
#define DD 164
#define HH 2
#define DKK 82
#define EDIM 16
#define TDIM 8
#define STEP 30000
#define NC 20          // EE / STEP
#define FEAT 24        // EDIM + TDIM
#define HID 82         // D/2
#define NG 41          // DD/4 float4 groups
#define KP 96          // padded K for MFMA (82 -> 96)
#define MP 336         // padded M (2*164 -> 336)
#define NBLK ((EE + 255) / 256)

typedef __attribute__((ext_vector_type(8))) short short8;
typedef __attribute__((ext_vector_type(4))) float floatx4;

__device__ __forceinline__ float fast_tanh(float x) {
    float e = __expf(2.0f * x);
    return 1.0f - 2.0f * __builtin_amdgcn_rcpf(e + 1.0f);
}

__device__ __forceinline__ short f2bf(float f) {
    union { float f; unsigned u; } x; x.f = f;
    unsigned r = x.u + 0x7fffu + ((x.u >> 16) & 1u);   // RNE
    return (short)(r >> 16);
}

// ---------------- one-time weight prep: W2 -> pair-interleaved bf16, b2 -> permuted ----------------

__global__ void __launch_bounds__(256) prep_w2_kernel(
    const float* __restrict__ W2, const float* __restrict__ b2,
    short* __restrict__ W2p, float* __restrict__ b2p)
{
    int idx = blockIdx.x * 256 + threadIdx.x;
    if (idx < MP * KP) {
        int m = idx / KP, kk = idx - m * KP;
        float val = 0.f;
        if (m < 2 * DD && kk < HID) {
            int dth = m >> 1, p = m & 1;
            val = W2[(size_t)(dth + p * DD) * HID + kk];
        }
        W2p[idx] = f2bf(val);
    }
    if (idx < MP) {
        float bv = 0.f;
        if (idx < 2 * DD) { int dth = idx >> 1, p = idx & 1; bv = b2[dth + p * DD]; }
        b2p[idx] = bv;
    }
}

// ---------------- CSR build ----------------

__global__ void __launch_bounds__(256) zero2_kernel(int* __restrict__ a, int* __restrict__ b, int n) {
    int i = blockIdx.x * 256 + threadIdx.x;
    if (i < n) { a[i] = 0; b[i] = 0; }
}

__global__ void __launch_bounds__(256) count_kernel(const int* __restrict__ ei, int* __restrict__ deg) {
    int e = blockIdx.x * 256 + threadIdx.x;
    if (e < EE) atomicAdd(&deg[ei[EE + e]], 1);
}

__global__ void __launch_bounds__(256) scan_kernel(const int* __restrict__ deg, int* __restrict__ off) {
    const int CH = (NN + 255) / 256;
    int t = threadIdx.x;
    int beg = t * CH, end = min(beg + CH, NN);
    int s = 0;
    for (int i = beg; i < end; ++i) s += deg[i];
    __shared__ int sums[256];
    sums[t] = s;
    __syncthreads();
    for (int d = 1; d < 256; d <<= 1) {
        int val = (t >= d) ? sums[t - d] : 0;
        __syncthreads();
        sums[t] += val;
        __syncthreads();
    }
    int run = (t == 0) ? 0 : sums[t - 1];
    for (int i = beg; i < end; ++i) { off[i] = run; run += deg[i]; }
    if (t == 255) off[NN] = run;
}

__global__ void __launch_bounds__(256) fill_kernel(const int* __restrict__ ei,
                                                   const int* __restrict__ off,
                                                   int* __restrict__ cnt,
                                                   int* __restrict__ elist) {
    int e = blockIdx.x * 256 + threadIdx.x;
    if (e >= EE) return;
    int d = ei[EE + e];
    int p = atomicAdd(&cnt[d], 1);
    elist[off[d] + p] = e;
}

// ---------------- score (dst-sorted gather order for q-row L1/L2 reuse) ----------------

__global__ void __launch_bounds__(256) score_sorted_kernel(
    const float* __restrict__ q, const float* __restrict__ k,
    const int* __restrict__ ei, const float* __restrict__ rel_bias,
    const int* __restrict__ elist, float* __restrict__ escore)
{
    int i = blockIdx.x * 256 + threadIdx.x;
    if (i >= EE) return;
    int e = elist[i];            // dst-sorted: consecutive threads share q rows
    int s = ei[e];
    int d = ei[EE + e];
    const float4* qr = (const float4*)(q + (size_t)d * DD);
    const float4* kr = (const float4*)(k + (size_t)s * DD);
    float s0 = 0.f, s1 = 0.f;
    #pragma unroll 4
    for (int j = 0; j < 20; ++j) {
        float4 a = qr[j], b = kr[j];
        s0 += a.x * b.x; s0 += a.y * b.y; s0 += a.z * b.z; s0 += a.w * b.w;
    }
    {
        float4 a = qr[20], b = kr[20];
        s0 += a.x * b.x + a.y * b.y;
        s1 += a.z * b.z + a.w * b.w;
    }
    #pragma unroll 4
    for (int j = 21; j < 41; ++j) {
        float4 a = qr[j], b = kr[j];
        s1 += a.x * b.x; s1 += a.y * b.y; s1 += a.z * b.z; s1 += a.w * b.w;
    }
    const float inv_sqrt = 0.11043152607484654f;  // 1/sqrt(82)
    escore[2 * e]     = __expf(s0 * inv_sqrt + rel_bias[0]);
    escore[2 * e + 1] = __expf(s1 * inv_sqrt + rel_bias[1]);
}

// original-order score for the fallback path
__global__ void __launch_bounds__(256) score_kernel(
    const float* __restrict__ q, const float* __restrict__ k,
    const int* __restrict__ ei, const float* __restrict__ rel_bias,
    float* __restrict__ escore)
{
    int e = blockIdx.x * 256 + threadIdx.x;
    if (e >= EE) return;
    int s = ei[e];
    int d = ei[EE + e];
    const float4* qr = (const float4*)(q + (size_t)d * DD);
    const float4* kr = (const float4*)(k + (size_t)s * DD);
    float s0 = 0.f, s1 = 0.f;
    #pragma unroll 4
    for (int i = 0; i < 20; ++i) {
        float4 a = qr[i], b = kr[i];
        s0 += a.x * b.x; s0 += a.y * b.y; s0 += a.z * b.z; s0 += a.w * b.w;
    }
    {
        float4 a = qr[20], b = kr[20];
        s0 += a.x * b.x + a.y * b.y;
        s1 += a.z * b.z + a.w * b.w;
    }
    #pragma unroll 4
    for (int i = 21; i < 41; ++i) {
        float4 a = qr[i], b = kr[i];
        s1 += a.x * b.x; s1 += a.y * b.y; s1 += a.z * b.z; s1 += a.w * b.w;
    }
    const float inv_sqrt = 0.11043152607484654f;  // 1/sqrt(82)
    escore[2 * e]     = __expf(s0 * inv_sqrt + rel_bias[0]);
    escore[2 * e + 1] = __expf(s1 * inv_sqrt + rel_bias[1]);
}

__global__ void __launch_bounds__(256) chunkinv_kernel(
    const float* __restrict__ escore, float* __restrict__ invsum)
{
    int c = blockIdx.x, h = blockIdx.y;
    const float* base = escore + (size_t)c * STEP * 2 + h;
    float acc = 0.f;
    for (int i = threadIdx.x; i < STEP; i += 256) acc += base[2 * i];
    __shared__ float red[256];
    red[threadIdx.x] = acc;
    __syncthreads();
    for (int s2 = 128; s2 > 0; s2 >>= 1) {
        if (threadIdx.x < s2) red[threadIdx.x] += red[threadIdx.x + s2];
        __syncthreads();
    }
    if (threadIdx.x == 0) invsum[c * 2 + h] = 1.0f / red[0];
}

__global__ void __launch_bounds__(256) zero_kernel(float4* __restrict__ p, int n4) {
    int i = blockIdx.x * 256 + threadIdx.x;
    if (i < n4) p[i] = make_float4(0.f, 0.f, 0.f, 0.f);
}

// ---------------- main kernel ----------------
// Changes vs round 1:
//  * LDS overlay: hmid (48KB, dead after bfrag load) unioned with double-buffered res
//    -> 53248 B total -> 3 blocks/CU (12 waves, was 2 blocks / 8 waves)
//  * double-buffered res -> ONE barrier per mt iteration (22 vs 42)
//  * ssrc/satt hoisted to registers once; v loads issued at top of each iteration
//    so afrag+MFMA+epilogue cover their ~600-900 cy latency

union ShOverlay {
    short hmid[256 * KP];      // 48 KB, [edge][k] bf16 (staging phase only)
    float res[2][256 * 8];     // 2 x 8 KB, [parity][edge][8 dims] (mt loop)
};

__global__ void __launch_bounds__(256) main_mfma_kernel(
    const float* __restrict__ v, const int* __restrict__ ei,
    const float* __restrict__ edge_attr, const float* __restrict__ edge_time,
    const float* __restrict__ Wt, const float* __restrict__ bt,
    const float* __restrict__ W1, const float* __restrict__ b1,
    const short* __restrict__ W2p, const float* __restrict__ b2p,
    const float* __restrict__ escore, const float* __restrict__ invsum,
    const int* __restrict__ off, const int* __restrict__ elist,
    float* __restrict__ out)
{
    __shared__ ShOverlay sh;
    __shared__ int   sdst[256];
    __shared__ int   ssrc[256];
    __shared__ float satt[512];

    const int tid = threadIdx.x;
    const int gid = blockIdx.x * 256 + tid;
    const bool valid = gid < EE;
    const int gi = valid ? gid : (EE - 1);
    const int e = elist[gi];
    const int s = ei[e];
    const int d = ei[EE + e];
    sdst[tid] = valid ? d : -1;
    ssrc[tid] = s;
    {
        unsigned c = (unsigned)e / STEP;
        satt[2 * tid]     = escore[2 * e]     * invsum[2 * c];
        satt[2 * tid + 1] = escore[2 * e + 1] * invsum[2 * c + 1];
    }

    // ---- feat ----
    float feat[FEAT];
    const float4* ea4 = (const float4*)(edge_attr + (size_t)e * EDIM);
    #pragma unroll
    for (int i = 0; i < 4; ++i) {
        float4 a = ea4[i];
        feat[4 * i + 0] = a.x; feat[4 * i + 1] = a.y;
        feat[4 * i + 2] = a.z; feat[4 * i + 3] = a.w;
    }
    float t = edge_time[e];
    #pragma unroll
    for (int j = 0; j < TDIM; ++j) feat[EDIM + j] = t * Wt[j] + bt[j];

    // ---- hmid in 8-wide chunks -> bf16 -> LDS ----
    #pragma unroll 1
    for (int oc = 0; oc < KP / 8; ++oc) {
        union { short h[8]; int4 v4; } pk;
        #pragma unroll
        for (int j = 0; j < 8; ++j) {
            int o = oc * 8 + j;
            float acc = 0.f;
            if (o < HID) {
                acc = b1[o];
                #pragma unroll
                for (int f = 0; f < FEAT; ++f) acc = fmaf(feat[f], W1[o * FEAT + f], acc);
                acc = fmaxf(acc, 0.f);
            }
            pk.h[j] = f2bf(acc);
        }
        *(int4*)&sh.hmid[tid * KP + oc * 8] = pk.v4;
    }
    __syncthreads();

    const int lane = tid & 63;
    const int wavebase = tid & ~63;
    const int lrow = lane & 15;
    const int quad = lane >> 4;

    // ---- B fragments: persistent across the whole mt loop (12 x 4 VGPRs) ----
    short8 bfrag[4][3];
    #pragma unroll
    for (int nt = 0; nt < 4; ++nt)
        #pragma unroll
        for (int ks = 0; ks < 3; ++ks)
            bfrag[nt][ks] = *(const short8*)&sh.hmid[(wavebase + nt * 16 + lrow) * KP + ks * 32 + quad * 8];

    // ---- per-nt hoisted state: src row index, both per-head att weights ----
    int   s_e[4];
    float a0h[4], a1h[4];
    #pragma unroll
    for (int nt = 0; nt < 4; ++nt) {
        int e_loc = wavebase + nt * 16 + lrow;
        s_e[nt] = ssrc[e_loc];
        a0h[nt] = satt[2 * e_loc];
        a1h[nt] = satt[2 * e_loc + 1];
    }

    // ---- leader metadata (dst-sorted segments) ----
    bool leader = valid && (tid == 0 || sdst[tid - 1] != d);
    int seglen = 0;
    bool interior = false;
    float* orow = nullptr;
    if (leader) {
        while (tid + seglen < 256 && sdst[tid + seglen] == d) ++seglen;
        int bs = blockIdx.x * 256;
        interior = (off[d] >= bs) && (off[d + 1] <= bs + 256);
        orow = out + (size_t)d * DD;
    }

    // overlay guard: all reads of sh.hmid complete before sh.res is written
    __syncthreads();

    int p = 0;
    #pragma unroll 1
    for (int mt = 0; mt < 21; ++mt) {
        const int d0 = mt * 8 + quad * 2;
        const bool dok = d0 < DD;

        // ---- scattered v loads issued FIRST (longest latency) ----
        float2 vv[4];
        #pragma unroll
        for (int nt = 0; nt < 4; ++nt) {
            if (dok) vv[nt] = *(const float2*)(v + (size_t)s_e[nt] * DD + d0);
            else     vv[nt] = make_float2(0.f, 0.f);
        }

        short8 afrag[3];
        #pragma unroll
        for (int ks = 0; ks < 3; ++ks)
            afrag[ks] = *(const short8*)&W2p[(mt * 16 + lrow) * KP + ks * 32 + quad * 8];

        floatx4 acc[4];
        #pragma unroll
        for (int nt = 0; nt < 4; ++nt) acc[nt] = (floatx4)(0.f);
        #pragma unroll
        for (int ks = 0; ks < 3; ++ks)
            #pragma unroll
            for (int nt = 0; nt < 4; ++nt)
                acc[nt] = __builtin_amdgcn_mfma_f32_16x16x32_bf16(afrag[ks], bfrag[nt][ks], acc[nt], 0, 0, 0);

        float4 bias = *(const float4*)&b2p[mt * 16 + quad * 4];
        const bool hi = d0 >= DKK;   // d0 even, DKK even: same head for d0 and d0+1

        #pragma unroll
        for (int nt = 0; nt < 4; ++nt) {
            int e_loc = wavebase + nt * 16 + lrow;
            float r0 = 0.f, r1 = 0.f;
            if (dok) {
                float g0  = fast_tanh(acc[nt][0] + bias.x);
                float be0 = fast_tanh(acc[nt][1] + bias.y);
                float g1  = fast_tanh(acc[nt][2] + bias.z);
                float be1 = fast_tanh(acc[nt][3] + bias.w);
                float a = hi ? a1h[nt] : a0h[nt];
                r0 = a * (vv[nt].x * (1.f + g0) + be0);
                r1 = a * (vv[nt].y * (1.f + g1) + be1);
            }
            sh.res[p][e_loc * 8 + quad * 2]     = r0;
            sh.res[p][e_loc * 8 + quad * 2 + 1] = r1;
        }
        __syncthreads();

        if (leader) {
            float4 s0 = make_float4(0.f, 0.f, 0.f, 0.f);
            float4 s1 = make_float4(0.f, 0.f, 0.f, 0.f);
            for (int t2 = 0; t2 < seglen; ++t2) {
                const float4* rp = (const float4*)&sh.res[p][(tid + t2) * 8];
                float4 a = rp[0], b = rp[1];
                s0.x += a.x; s0.y += a.y; s0.z += a.z; s0.w += a.w;
                s1.x += b.x; s1.y += b.y; s1.z += b.z; s1.w += b.w;
            }
            int D0 = mt * 8;
            if (interior) {
                *(float4*)(orow + D0) = s0;
                if (D0 + 4 < DD) *(float4*)(orow + D0 + 4) = s1;
            } else {
                unsafeAtomicAdd(orow + D0 + 0, s0.x);
                unsafeAtomicAdd(orow + D0 + 1, s0.y);
                unsafeAtomicAdd(orow + D0 + 2, s0.z);
                unsafeAtomicAdd(orow + D0 + 3, s0.w);
                if (D0 + 4 < DD) {
                    unsafeAtomicAdd(orow + D0 + 4, s1.x);
                    unsafeAtomicAdd(orow + D0 + 5, s1.y);
                    unsafeAtomicAdd(orow + D0 + 6, s1.z);
                    unsafeAtomicAdd(orow + D0 + 7, s1.w);
                }
            }
        }
        p ^= 1;   // double-buffer: next iteration writes the other half, no 2nd barrier
    }
}

// ---------------- fallback (proved-correct round-1 atomic path) ----------------

__global__ void __launch_bounds__(256) main_atomic_kernel(
    const float* __restrict__ v, const int* __restrict__ ei,
    const float* __restrict__ edge_attr, const float* __restrict__ edge_time,
    const float* __restrict__ Wt, const float* __restrict__ bt,
    const float* __restrict__ W1, const float* __restrict__ b1,
    const float* __restrict__ W2, const float* __restrict__ b2,
    const float* __restrict__ escore, const float* __restrict__ invsum,
    float* __restrict__ out)
{
    int e = blockIdx.x * 256 + threadIdx.x;
    if (e >= EE) return;
    int s = ei[e];
    int d = ei[EE + e];
    float feat[FEAT];
    const float4* ea4 = (const float4*)(edge_attr + (size_t)e * EDIM);
    #pragma unroll
    for (int i = 0; i < 4; ++i) {
        float4 a = ea4[i];
        feat[4 * i + 0] = a.x; feat[4 * i + 1] = a.y;
        feat[4 * i + 2] = a.z; feat[4 * i + 3] = a.w;
    }
    float t = edge_time[e];
    #pragma unroll
    for (int j = 0; j < TDIM; ++j) feat[EDIM + j] = t * Wt[j] + bt[j];
    float hmid[HID];
    #pragma unroll
    for (int o = 0; o < HID; ++o) {
        float acc = b1[o];
        #pragma unroll
        for (int f = 0; f < FEAT; ++f) acc = fmaf(feat[f], W1[o * FEAT + f], acc);
        hmid[o] = fmaxf(acc, 0.f);
    }
    int c = e / STEP;
    float att0 = escore[2 * e]     * invsum[2 * c];
    float att1 = escore[2 * e + 1] * invsum[2 * c + 1];
    const float4* vrow4 = (const float4*)(v + (size_t)s * DD);
    float* orow = out + (size_t)d * DD;
    #pragma unroll 1
    for (int j = 0; j < NG; ++j) {
        float4 vv = vrow4[j];
        float vvals[4] = {vv.x, vv.y, vv.z, vv.w};
        float res[4];
        #pragma unroll
        for (int u = 0; u < 4; ++u) {
            int dd = 4 * j + u;
            float ga = b2[dd];
            float bb = b2[dd + DD];
            #pragma unroll
            for (int o = 0; o < HID; ++o) {
                ga = fmaf(hmid[o], W2[dd * HID + o], ga);
                bb = fmaf(hmid[o], W2[(dd + DD) * HID + o], bb);
            }
            float gamma = fast_tanh(ga);
            float beta  = fast_tanh(bb);
            float vh = vvals[u] * (1.f + gamma) + beta;
            res[u] = ((dd < DKK) ? att0 : att1) * vh;
        }
        unsafeAtomicAdd(orow + 4 * j + 0, res[0]);
        unsafeAtomicAdd(orow + 4 * j + 1, res[1]);
        unsafeAtomicAdd(orow + 4 * j + 2, res[2]);
        unsafeAtomicAdd(orow + 4 * j + 3, res[3]);
    }
}

// ---------------- launch ----------------

extern "C" void kernel_launch(void* const* d_in, const int* in_sizes, int n_in,
                              void* d_out, int out_size, void* d_ws, size_t ws_size,
                              hipStream_t stream) {
    const float* q   = (const float*)d_in[0];
    const float* k   = (const float*)d_in[1];
    const float* v   = (const float*)d_in[2];
    const int*   ei  = (const int*)d_in[3];
    const float* ea  = (const float*)d_in[4];
    const float* et  = (const float*)d_in[5];
    const float* Wt  = (const float*)d_in[6];
    const float* bt  = (const float*)d_in[7];
    const float* W1  = (const float*)d_in[8];
    const float* b1  = (const float*)d_in[9];
    const float* W2  = (const float*)d_in[10];
    const float* b2  = (const float*)d_in[11];
    const float* rb  = (const float*)d_in[12];
    float* out = (float*)d_out;

    // ws layout (16-B aligned chunks), ~9.7 MB total
    short* W2p    = (short*)d_ws;                       // 336*96 shorts = 64512 B
    float* b2p    = (float*)(W2p + MP * KP);            // 336 floats = 1344 B
    float* escore = b2p + MP;                           // 2*EE
    float* invsum = escore + (size_t)2 * EE;            // 64 (padded)
    int*   deg    = (int*)(invsum + 64);                // NN
    int*   off    = deg + NN;                           // NN+1
    int*   cnt    = off + NN + 1;                       // NN
    int*   elist  = cnt + NN;                           // EE

    size_t need = (size_t)(MP * KP) * 2 + (MP + 2 * EE + 64) * 4 +
                  ((size_t)3 * NN + 1 + EE) * 4;

    int n4 = out_size / 4;
    zero_kernel<<<(n4 + 255) / 256, 256, 0, stream>>>((float4*)out, n4);

    if (ws_size >= need) {
        prep_w2_kernel<<<(MP * KP + 255) / 256, 256, 0, stream>>>(W2, b2, W2p, b2p);
        // CSR build first so score can gather in dst-sorted order
        zero2_kernel<<<(NN + 255) / 256, 256, 0, stream>>>(deg, cnt, NN);
        count_kernel<<<NBLK, 256, 0, stream>>>(ei, deg);
        scan_kernel<<<1, 256, 0, stream>>>(deg, off);
        fill_kernel<<<NBLK, 256, 0, stream>>>(ei, off, cnt, elist);
        score_sorted_kernel<<<NBLK, 256, 0, stream>>>(q, k, ei, rb, elist, escore);
        chunkinv_kernel<<<dim3(NC, HH), 256, 0, stream>>>(escore, invsum);
        main_mfma_kernel<<<NBLK, 256, 0, stream>>>(
            v, ei, ea, et, Wt, bt, W1, b1, W2p, b2p, escore, invsum, off, elist, out);
    } else {
        float* escore_f = (float*)d_ws;
        float* invsum_f = escore_f + (size_t)2 * EE;
        score_kernel<<<NBLK, 256, 0, stream>>>(q, k, ei, rb, escore_f);
        chunkinv_kernel<<<dim3(NC, HH), 256, 0, stream>>>(escore_f, invsum_f);
        main_atomic_kernel<<<NBLK, 256, 0, stream>>>(
            v, ei, ea, et, Wt, bt, W1, b1, W2, b2, escore_f, invsum_f, out);
    }
}

// Round 3
// 964.217 us; speedup vs baseline: 1.1151x; 1.0722x over previous
//
#include <hip/hip_runtime.h>

#define NN 100000
#define EE 600000
#define DD 164
#define HH 2
#define DKK 82
#define EDIM 16
#define TDIM 8
#define STEP 30000
#define NC 20          // EE / STEP
#define FEAT 24        // EDIM + TDIM
#define HID 82         // D/2
#define NG 41          // DD/4 float4 groups
#define KP 96          // padded K for MFMA (82 -> 96)
#define MP 336         // padded M (2*164 -> 336)
#define NBLK ((EE + 255) / 256)

typedef __attribute__((ext_vector_type(8))) short short8;
typedef __attribute__((ext_vector_type(4))) float floatx4;

__device__ __forceinline__ float fast_tanh(float x) {
    float e = __expf(2.0f * x);
    return 1.0f - 2.0f * __builtin_amdgcn_rcpf(e + 1.0f);
}

__device__ __forceinline__ short f2bf(float f) {
    union { float f; unsigned u; } x; x.f = f;
    unsigned r = x.u + 0x7fffu + ((x.u >> 16) & 1u);   // RNE
    return (short)(r >> 16);
}

// ---------------- one-time weight prep: W2 -> pair-interleaved bf16, b2 -> permuted ----------------

__global__ void __launch_bounds__(256) prep_w2_kernel(
    const float* __restrict__ W2, const float* __restrict__ b2,
    short* __restrict__ W2p, float* __restrict__ b2p)
{
    int idx = blockIdx.x * 256 + threadIdx.x;
    if (idx < MP * KP) {
        int m = idx / KP, kk = idx - m * KP;
        float val = 0.f;
        if (m < 2 * DD && kk < HID) {
            int dth = m >> 1, p = m & 1;
            val = W2[(size_t)(dth + p * DD) * HID + kk];
        }
        W2p[idx] = f2bf(val);
    }
    if (idx < MP) {
        float bv = 0.f;
        if (idx < 2 * DD) { int dth = idx >> 1, p = idx & 1; bv = b2[dth + p * DD]; }
        b2p[idx] = bv;
    }
}

// ---------------- CSR build ----------------

__global__ void __launch_bounds__(256) zero2_kernel(int* __restrict__ a, int* __restrict__ b, int n) {
    int i = blockIdx.x * 256 + threadIdx.x;
    if (i < n) { a[i] = 0; b[i] = 0; }
}

__global__ void __launch_bounds__(256) count_kernel(const int* __restrict__ ei, int* __restrict__ deg) {
    int e = blockIdx.x * 256 + threadIdx.x;
    if (e < EE) atomicAdd(&deg[ei[EE + e]], 1);
}

__global__ void __launch_bounds__(256) scan_kernel(const int* __restrict__ deg, int* __restrict__ off) {
    const int CH = (NN + 255) / 256;
    int t = threadIdx.x;
    int beg = t * CH, end = min(beg + CH, NN);
    int s = 0;
    for (int i = beg; i < end; ++i) s += deg[i];
    __shared__ int sums[256];
    sums[t] = s;
    __syncthreads();
    for (int d = 1; d < 256; d <<= 1) {
        int val = (t >= d) ? sums[t - d] : 0;
        __syncthreads();
        sums[t] += val;
        __syncthreads();
    }
    int run = (t == 0) ? 0 : sums[t - 1];
    for (int i = beg; i < end; ++i) { off[i] = run; run += deg[i]; }
    if (t == 255) off[NN] = run;
}

__global__ void __launch_bounds__(256) fill_kernel(const int* __restrict__ ei,
                                                   const int* __restrict__ off,
                                                   int* __restrict__ cnt,
                                                   int* __restrict__ elist) {
    int e = blockIdx.x * 256 + threadIdx.x;
    if (e >= EE) return;
    int d = ei[EE + e];
    int p = atomicAdd(&cnt[d], 1);
    elist[off[d] + p] = e;
}

// ---------------- score: 16-lane cooperative, coalesced row reads ----------------
// 16 lanes share one edge. Lane gl reads float4 idx = gl + 16*jj (jj=0..2, idx<41):
// per instruction the 16-lane group reads 256 B contiguous (coalesced), so a 656-B
// row costs its minimal ~6 line-touches instead of 64 lines/instruction in the
// old one-thread-per-edge scatter. Head split at float index 82 = float4 idx 20.5:
//   idx<20 -> head0, idx>20 -> head1, idx==20 -> lo pair head0, hi pair head1.
// dst-sorted elist order retained: consecutive groups share q rows (L1 hits).

__global__ void __launch_bounds__(256) score_coop_kernel(
    const float* __restrict__ q, const float* __restrict__ k,
    const int* __restrict__ ei, const float* __restrict__ rel_bias,
    const int* __restrict__ elist, float* __restrict__ escore)
{
    const int tid = threadIdx.x;
    const int grp = tid >> 4;          // 16 edge-groups per block
    const int gl  = tid & 15;
    int i = blockIdx.x * 16 + grp;     // dst-sorted edge slot
    if (i >= EE) return;
    int e = elist[i];
    int sn = ei[e];
    int dn = ei[EE + e];
    const float4* qr = (const float4*)(q + (size_t)dn * DD);
    const float4* kr = (const float4*)(k + (size_t)sn * DD);
    float s0 = 0.f, s1 = 0.f;
    #pragma unroll
    for (int jj = 0; jj < 3; ++jj) {
        int idx = gl + 16 * jj;
        if (idx < 41) {
            float4 a = qr[idx], b = kr[idx];
            float lo = a.x * b.x + a.y * b.y;
            float hi = a.z * b.z + a.w * b.w;
            s0 += (idx < 20 ? hi : 0.f) + (idx <= 20 ? lo : 0.f);
            s1 += (idx > 20 ? lo : 0.f) + (idx >= 20 ? hi : 0.f);
        }
    }
    #pragma unroll
    for (int m = 1; m < 16; m <<= 1) {
        s0 += __shfl_xor(s0, m, 64);
        s1 += __shfl_xor(s1, m, 64);
    }
    if (gl == 0) {
        const float inv_sqrt = 0.11043152607484654f;  // 1/sqrt(82)
        escore[2 * e]     = __expf(s0 * inv_sqrt + rel_bias[0]);
        escore[2 * e + 1] = __expf(s1 * inv_sqrt + rel_bias[1]);
    }
}

// original-order score for the fallback path
__global__ void __launch_bounds__(256) score_kernel(
    const float* __restrict__ q, const float* __restrict__ k,
    const int* __restrict__ ei, const float* __restrict__ rel_bias,
    float* __restrict__ escore)
{
    int e = blockIdx.x * 256 + threadIdx.x;
    if (e >= EE) return;
    int s = ei[e];
    int d = ei[EE + e];
    const float4* qr = (const float4*)(q + (size_t)d * DD);
    const float4* kr = (const float4*)(k + (size_t)s * DD);
    float s0 = 0.f, s1 = 0.f;
    #pragma unroll 4
    for (int i = 0; i < 20; ++i) {
        float4 a = qr[i], b = kr[i];
        s0 += a.x * b.x; s0 += a.y * b.y; s0 += a.z * b.z; s0 += a.w * b.w;
    }
    {
        float4 a = qr[20], b = kr[20];
        s0 += a.x * b.x + a.y * b.y;
        s1 += a.z * b.z + a.w * b.w;
    }
    #pragma unroll 4
    for (int i = 21; i < 41; ++i) {
        float4 a = qr[i], b = kr[i];
        s1 += a.x * b.x; s1 += a.y * b.y; s1 += a.z * b.z; s1 += a.w * b.w;
    }
    const float inv_sqrt = 0.11043152607484654f;  // 1/sqrt(82)
    escore[2 * e]     = __expf(s0 * inv_sqrt + rel_bias[0]);
    escore[2 * e + 1] = __expf(s1 * inv_sqrt + rel_bias[1]);
}

__global__ void __launch_bounds__(256) chunkinv_kernel(
    const float* __restrict__ escore, float* __restrict__ invsum)
{
    int c = blockIdx.x, h = blockIdx.y;
    const float* base = escore + (size_t)c * STEP * 2 + h;
    float acc = 0.f;
    for (int i = threadIdx.x; i < STEP; i += 256) acc += base[2 * i];
    __shared__ float red[256];
    red[threadIdx.x] = acc;
    __syncthreads();
    for (int s2 = 128; s2 > 0; s2 >>= 1) {
        if (threadIdx.x < s2) red[threadIdx.x] += red[threadIdx.x + s2];
        __syncthreads();
    }
    if (threadIdx.x == 0) invsum[c * 2 + h] = 1.0f / red[0];
}

__global__ void __launch_bounds__(256) zero_kernel(float4* __restrict__ p, int n4) {
    int i = blockIdx.x * 256 + threadIdx.x;
    if (i < n4) p[i] = make_float4(0.f, 0.f, 0.f, 0.f);
}

// ---------------- main: round-1 proven structure (447 us) ----------------

__global__ void __launch_bounds__(256) main_mfma_kernel(
    const float* __restrict__ v, const int* __restrict__ ei,
    const float* __restrict__ edge_attr, const float* __restrict__ edge_time,
    const float* __restrict__ Wt, const float* __restrict__ bt,
    const float* __restrict__ W1, const float* __restrict__ b1,
    const short* __restrict__ W2p, const float* __restrict__ b2p,
    const float* __restrict__ escore, const float* __restrict__ invsum,
    const int* __restrict__ off, const int* __restrict__ elist,
    float* __restrict__ out)
{
    __shared__ short hmid_lds[256 * KP];   // 48 KB, row-major [edge][k] bf16
    __shared__ float res_lds[256 * 8];     // 8 KB, [edge][8 dims of current mt]
    __shared__ int   sdst[256];
    __shared__ int   ssrc[256];
    __shared__ float satt[512];

    const int tid = threadIdx.x;
    const int gid = blockIdx.x * 256 + tid;
    const bool valid = gid < EE;
    const int gi = valid ? gid : (EE - 1);
    const int e = elist[gi];
    const int s = ei[e];
    const int d = ei[EE + e];
    sdst[tid] = valid ? d : -1;
    ssrc[tid] = s;
    {
        unsigned c = (unsigned)e / STEP;
        satt[2 * tid]     = escore[2 * e]     * invsum[2 * c];
        satt[2 * tid + 1] = escore[2 * e + 1] * invsum[2 * c + 1];
    }

    // ---- feat ----
    float feat[FEAT];
    const float4* ea4 = (const float4*)(edge_attr + (size_t)e * EDIM);
    #pragma unroll
    for (int i = 0; i < 4; ++i) {
        float4 a = ea4[i];
        feat[4 * i + 0] = a.x; feat[4 * i + 1] = a.y;
        feat[4 * i + 2] = a.z; feat[4 * i + 3] = a.w;
    }
    float t = edge_time[e];
    #pragma unroll
    for (int j = 0; j < TDIM; ++j) feat[EDIM + j] = t * Wt[j] + bt[j];

    // ---- hmid in 8-wide chunks -> bf16 -> LDS ----
    #pragma unroll 1
    for (int oc = 0; oc < KP / 8; ++oc) {
        union { short h[8]; int4 v4; } pk;
        #pragma unroll
        for (int j = 0; j < 8; ++j) {
            int o = oc * 8 + j;
            float acc = 0.f;
            if (o < HID) {
                acc = b1[o];
                #pragma unroll
                for (int f = 0; f < FEAT; ++f) acc = fmaf(feat[f], W1[o * FEAT + f], acc);
                acc = fmaxf(acc, 0.f);
            }
            pk.h[j] = f2bf(acc);
        }
        *(int4*)&hmid_lds[tid * KP + oc * 8] = pk.v4;
    }
    __syncthreads();

    const int lane = tid & 63;
    const int wavebase = tid & ~63;
    const int lrow = lane & 15;
    const int quad = lane >> 4;

    // ---- B fragments: persistent across the whole mt loop (12 x 4 VGPRs) ----
    short8 bfrag[4][3];
    #pragma unroll
    for (int nt = 0; nt < 4; ++nt)
        #pragma unroll
        for (int ks = 0; ks < 3; ++ks)
            bfrag[nt][ks] = *(const short8*)&hmid_lds[(wavebase + nt * 16 + lrow) * KP + ks * 32 + quad * 8];

    // ---- leader metadata (dst-sorted segments) ----
    bool leader = valid && (tid == 0 || sdst[tid - 1] != d);
    int seglen = 0;
    bool interior = false;
    float* orow = nullptr;
    if (leader) {
        while (tid + seglen < 256 && sdst[tid + seglen] == d) ++seglen;
        int bs = blockIdx.x * 256;
        interior = (off[d] >= bs) && (off[d + 1] <= bs + 256);
        orow = out + (size_t)d * DD;
    }

    #pragma unroll 1
    for (int mt = 0; mt < 21; ++mt) {
        short8 afrag[3];
        #pragma unroll
        for (int ks = 0; ks < 3; ++ks)
            afrag[ks] = *(const short8*)&W2p[(mt * 16 + lrow) * KP + ks * 32 + quad * 8];

        floatx4 acc[4];
        #pragma unroll
        for (int nt = 0; nt < 4; ++nt) acc[nt] = (floatx4)(0.f);
        #pragma unroll
        for (int ks = 0; ks < 3; ++ks)
            #pragma unroll
            for (int nt = 0; nt < 4; ++nt)
                acc[nt] = __builtin_amdgcn_mfma_f32_16x16x32_bf16(afrag[ks], bfrag[nt][ks], acc[nt], 0, 0, 0);

        float4 bias = *(const float4*)&b2p[mt * 16 + quad * 4];
        int d0 = mt * 8 + quad * 2;

        #pragma unroll
        for (int nt = 0; nt < 4; ++nt) {
            int e_loc = wavebase + nt * 16 + lrow;
            float r0 = 0.f, r1 = 0.f;
            if (d0 < DD) {
                float g0  = fast_tanh(acc[nt][0] + bias.x);
                float be0 = fast_tanh(acc[nt][1] + bias.y);
                float g1  = fast_tanh(acc[nt][2] + bias.z);
                float be1 = fast_tanh(acc[nt][3] + bias.w);
                int s_e = ssrc[e_loc];
                const float* vp = v + (size_t)s_e * DD + d0;
                float v0 = vp[0], v1 = vp[1];
                float a0 = satt[2 * e_loc + (d0 >= DKK ? 1 : 0)];
                float a1 = satt[2 * e_loc + (d0 + 1 >= DKK ? 1 : 0)];
                r0 = a0 * (v0 * (1.f + g0) + be0);
                r1 = a1 * (v1 * (1.f + g1) + be1);
            }
            res_lds[e_loc * 8 + quad * 2]     = r0;
            res_lds[e_loc * 8 + quad * 2 + 1] = r1;
        }
        __syncthreads();

        if (leader) {
            float4 s0 = make_float4(0.f, 0.f, 0.f, 0.f);
            float4 s1 = make_float4(0.f, 0.f, 0.f, 0.f);
            for (int t2 = 0; t2 < seglen; ++t2) {
                const float4* rp = (const float4*)&res_lds[(tid + t2) * 8];
                float4 a = rp[0], b = rp[1];
                s0.x += a.x; s0.y += a.y; s0.z += a.z; s0.w += a.w;
                s1.x += b.x; s1.y += b.y; s1.z += b.z; s1.w += b.w;
            }
            int D0 = mt * 8;
            if (interior) {
                *(float4*)(orow + D0) = s0;
                if (D0 + 4 < DD) *(float4*)(orow + D0 + 4) = s1;
            } else {
                unsafeAtomicAdd(orow + D0 + 0, s0.x);
                unsafeAtomicAdd(orow + D0 + 1, s0.y);
                unsafeAtomicAdd(orow + D0 + 2, s0.z);
                unsafeAtomicAdd(orow + D0 + 3, s0.w);
                if (D0 + 4 < DD) {
                    unsafeAtomicAdd(orow + D0 + 4, s1.x);
                    unsafeAtomicAdd(orow + D0 + 5, s1.y);
                    unsafeAtomicAdd(orow + D0 + 6, s1.z);
                    unsafeAtomicAdd(orow + D0 + 7, s1.w);
                }
            }
        }
        __syncthreads();
    }
}

// ---------------- fallback (proved-correct round-1 atomic path) ----------------

__global__ void __launch_bounds__(256) main_atomic_kernel(
    const float* __restrict__ v, const int* __restrict__ ei,
    const float* __restrict__ edge_attr, const float* __restrict__ edge_time,
    const float* __restrict__ Wt, const float* __restrict__ bt,
    const float* __restrict__ W1, const float* __restrict__ b1,
    const float* __restrict__ W2, const float* __restrict__ b2,
    const float* __restrict__ escore, const float* __restrict__ invsum,
    float* __restrict__ out)
{
    int e = blockIdx.x * 256 + threadIdx.x;
    if (e >= EE) return;
    int s = ei[e];
    int d = ei[EE + e];
    float feat[FEAT];
    const float4* ea4 = (const float4*)(edge_attr + (size_t)e * EDIM);
    #pragma unroll
    for (int i = 0; i < 4; ++i) {
        float4 a = ea4[i];
        feat[4 * i + 0] = a.x; feat[4 * i + 1] = a.y;
        feat[4 * i + 2] = a.z; feat[4 * i + 3] = a.w;
    }
    float t = edge_time[e];
    #pragma unroll
    for (int j = 0; j < TDIM; ++j) feat[EDIM + j] = t * Wt[j] + bt[j];
    float hmid[HID];
    #pragma unroll
    for (int o = 0; o < HID; ++o) {
        float acc = b1[o];
        #pragma unroll
        for (int f = 0; f < FEAT; ++f) acc = fmaf(feat[f], W1[o * FEAT + f], acc);
        hmid[o] = fmaxf(acc, 0.f);
    }
    int c = e / STEP;
    float att0 = escore[2 * e]     * invsum[2 * c];
    float att1 = escore[2 * e + 1] * invsum[2 * c + 1];
    const float4* vrow4 = (const float4*)(v + (size_t)s * DD);
    float* orow = out + (size_t)d * DD;
    #pragma unroll 1
    for (int j = 0; j < NG; ++j) {
        float4 vv = vrow4[j];
        float vvals[4] = {vv.x, vv.y, vv.z, vv.w};
        float res[4];
        #pragma unroll
        for (int u = 0; u < 4; ++u) {
            int dd = 4 * j + u;
            float ga = b2[dd];
            float bb = b2[dd + DD];
            #pragma unroll
            for (int o = 0; o < HID; ++o) {
                ga = fmaf(hmid[o], W2[dd * HID + o], ga);
                bb = fmaf(hmid[o], W2[(dd + DD) * HID + o], bb);
            }
            float gamma = fast_tanh(ga);
            float beta  = fast_tanh(bb);
            float vh = vvals[u] * (1.f + gamma) + beta;
            res[u] = ((dd < DKK) ? att0 : att1) * vh;
        }
        unsafeAtomicAdd(orow + 4 * j + 0, res[0]);
        unsafeAtomicAdd(orow + 4 * j + 1, res[1]);
        unsafeAtomicAdd(orow + 4 * j + 2, res[2]);
        unsafeAtomicAdd(orow + 4 * j + 3, res[3]);
    }
}

// ---------------- launch ----------------

extern "C" void kernel_launch(void* const* d_in, const int* in_sizes, int n_in,
                              void* d_out, int out_size, void* d_ws, size_t ws_size,
                              hipStream_t stream) {
    const float* q   = (const float*)d_in[0];
    const float* k   = (const float*)d_in[1];
    const float* v   = (const float*)d_in[2];
    const int*   ei  = (const int*)d_in[3];
    const float* ea  = (const float*)d_in[4];
    const float* et  = (const float*)d_in[5];
    const float* Wt  = (const float*)d_in[6];
    const float* bt  = (const float*)d_in[7];
    const float* W1  = (const float*)d_in[8];
    const float* b1  = (const float*)d_in[9];
    const float* W2  = (const float*)d_in[10];
    const float* b2  = (const float*)d_in[11];
    const float* rb  = (const float*)d_in[12];
    float* out = (float*)d_out;

    // ws layout (16-B aligned chunks), ~9.7 MB total
    short* W2p    = (short*)d_ws;                       // 336*96 shorts = 64512 B
    float* b2p    = (float*)(W2p + MP * KP);            // 336 floats = 1344 B
    float* escore = b2p + MP;                           // 2*EE
    float* invsum = escore + (size_t)2 * EE;            // 64 (padded)
    int*   deg    = (int*)(invsum + 64);                // NN
    int*   off    = deg + NN;                           // NN+1
    int*   cnt    = off + NN + 1;                       // NN
    int*   elist  = cnt + NN;                           // EE

    size_t need = (size_t)(MP * KP) * 2 + (MP + 2 * EE + 64) * 4 +
                  ((size_t)3 * NN + 1 + EE) * 4;

    int n4 = out_size / 4;
    zero_kernel<<<(n4 + 255) / 256, 256, 0, stream>>>((float4*)out, n4);

    if (ws_size >= need) {
        prep_w2_kernel<<<(MP * KP + 255) / 256, 256, 0, stream>>>(W2, b2, W2p, b2p);
        // CSR build first so score can gather in dst-sorted order
        zero2_kernel<<<(NN + 255) / 256, 256, 0, stream>>>(deg, cnt, NN);
        count_kernel<<<NBLK, 256, 0, stream>>>(ei, deg);
        scan_kernel<<<1, 256, 0, stream>>>(deg, off);
        fill_kernel<<<NBLK, 256, 0, stream>>>(ei, off, cnt, elist);
        score_coop_kernel<<<(EE + 15) / 16, 256, 0, stream>>>(q, k, ei, rb, elist, escore);
        chunkinv_kernel<<<dim3(NC, HH), 256, 0, stream>>>(escore, invsum);
        main_mfma_kernel<<<NBLK, 256, 0, stream>>>(
            v, ei, ea, et, Wt, bt, W1, b1, W2p, b2p, escore, invsum, off, elist, out);
    } else {
        float* escore_f = (float*)d_ws;
        float* invsum_f = escore_f + (size_t)2 * EE;
        score_kernel<<<NBLK, 256, 0, stream>>>(q, k, ei, rb, escore_f);
        chunkinv_kernel<<<dim3(NC, HH), 256, 0, stream>>>(escore_f, invsum_f);
        main_atomic_kernel<<<NBLK, 256, 0, stream>>>(
            v, ei, ea, et, Wt, bt, W1, b1, W2, b2, escore_f, invsum_f, out);
    }
}